// Round 5
// baseline (259.971 us; speedup 1.0000x reference)
//
#include <hip/hip_runtime.h>
#include <hip/hip_bf16.h>
#include <math.h>

using bf16 = __hip_bfloat16;
typedef __bf16 bf16x8 __attribute__((ext_vector_type(8)));
typedef float  f32x4  __attribute__((ext_vector_type(4)));
typedef unsigned short ushort8 __attribute__((ext_vector_type(8)));
typedef unsigned uint2v __attribute__((ext_vector_type(2)));

#define DEV __device__ __forceinline__

DEV void gld_lds16(const void* g, void* l) {
    __builtin_amdgcn_global_load_lds((const __attribute__((address_space(1))) void*)g,
                                     (__attribute__((address_space(3))) void*)l,
                                     16, 0, 0);
}

// ---------------- cast fp32 -> bf16 (flat) ----------------
__global__ __launch_bounds__(256) void cast_f32_bf16(const float* __restrict__ in,
                                                     bf16* __restrict__ out, int n4) {
    int i = blockIdx.x * blockDim.x + threadIdx.x;
    if (i >= n4) return;
    float4 f = ((const float4*)in)[i];
    __align__(8) bf16 o[4] = {__float2bfloat16(f.x), __float2bfloat16(f.y),
                              __float2bfloat16(f.z), __float2bfloat16(f.w)};
    ((uint64_t*)out)[i] = *(const uint64_t*)o;
}

// ---------------- transpose + cast: in fp32 [R][Cn] -> out bf16 [Cn][R] ----------------
__global__ __launch_bounds__(256) void transpose_cast(const float* __restrict__ in,
                                                      bf16* __restrict__ out, int R, int Cn) {
    __shared__ float tile[32][33];
    int bx = blockIdx.x * 32;
    int by = blockIdx.y * 32;
    int tx = threadIdx.x & 31, ty = threadIdx.x >> 5;
    for (int i = ty; i < 32; i += 8)
        tile[i][tx] = in[(size_t)(by + i) * Cn + bx + tx];
    __syncthreads();
    for (int i = ty; i < 32; i += 8)
        out[(size_t)(bx + i) * R + by + tx] = __float2bfloat16(tile[tx][i]);
}

// ---------------- GEMM1: qkv = x @ w_qkv + b -> q (prescaled), k, vT ----------------
// K-loop pipelined like flash_attn: double-buffered Al/Bl, ONE __syncthreads
// per K-step which (a) drains tile t's gld_lds issued one full compute phase
// earlier and (b) orders iter t-1's fragment reads vs the stage(t+1) writes
// into the other buffer. Staging latency hidden under MFMA; one barrier per
// K-step instead of two full-drain barriers.
__global__ __launch_bounds__(256) void gemm_qkv(const bf16* __restrict__ A,
                                                const bf16* __restrict__ Bt,
                                                const float* __restrict__ bias,
                                                bf16* __restrict__ qb,
                                                bf16* __restrict__ kb,
                                                bf16* __restrict__ vTb) {
    constexpr int K = 1024, T = 2048;
    constexpr float CS = 0.18033688f;  // 0.125 * log2(e)
    __shared__ __align__(16) bf16 Al[2][128 * 32];
    __shared__ __align__(16) bf16 Bl[2][128 * 32];
    __shared__ __align__(16) bf16 Et[32 * 136];  // epilogue staging, pad->272B rows
    int tid = threadIdx.x;
    int lane = tid & 63, w = tid >> 6;
    int wm = w >> 1, wn = w & 1;
    int l15 = lane & 15, quad = lane >> 4;
    int m0 = blockIdx.x * 128, n0 = blockIdx.y * 128;
    int l3 = l15 & 3;

    // staging geometry (per thread, 2 chunks per array)
    int e0 = tid * 8, e1 = (256 + tid) * 8;
    int r0 = e0 >> 5, cs0 = ((((e0 >> 3) & 3) ^ (r0 & 3)) << 3);
    int r1 = e1 >> 5, cs1 = ((((e1 >> 3) & 3) ^ (r1 & 3)) << 3);

    f32x4 acc[4][4] = {};
    // prologue: stage K-tile 0 into buffer 0
    gld_lds16(A  + (size_t)(m0 + r0) * K + cs0, &Al[0][e0]);
    gld_lds16(Bt + (size_t)(n0 + r0) * K + cs0, &Bl[0][e0]);
    gld_lds16(A  + (size_t)(m0 + r1) * K + cs1, &Al[0][e1]);
    gld_lds16(Bt + (size_t)(n0 + r1) * K + cs1, &Bl[0][e1]);

    for (int t = 0; t < K / 32; ++t) {
        int cur = t & 1;
        // drains vmcnt(0): tile t staged everywhere; prev-iter reads done
        __syncthreads();
        if (t + 1 < K / 32) {  // prefetch tile t+1; flies under tile t compute
            int k2 = (t + 1) * 32, nxt = cur ^ 1;
            gld_lds16(A  + (size_t)(m0 + r0) * K + k2 + cs0, &Al[nxt][e0]);
            gld_lds16(Bt + (size_t)(n0 + r0) * K + k2 + cs0, &Bl[nxt][e0]);
            gld_lds16(A  + (size_t)(m0 + r1) * K + k2 + cs1, &Al[nxt][e1]);
            gld_lds16(Bt + (size_t)(n0 + r1) * K + k2 + cs1, &Bl[nxt][e1]);
        }
        bf16x8 af[4], bfr[4];
        for (int i = 0; i < 4; ++i)
            af[i] = *(const bf16x8*)&Al[cur][(wm * 64 + i * 16 + l15) * 32 + ((quad ^ l3) << 3)];
        for (int j = 0; j < 4; ++j)
            bfr[j] = *(const bf16x8*)&Bl[cur][(wn * 64 + j * 16 + l15) * 32 + ((quad ^ l3) << 3)];
        for (int i = 0; i < 4; ++i)
            for (int j = 0; j < 4; ++j)
                acc[i][j] = __builtin_amdgcn_mfma_f32_16x16x32_bf16(af[i], bfr[j], acc[i][j], 0, 0, 0);
    }

    int mode = (blockIdx.y < 8) ? 0 : (blockIdx.y < 16 ? 1 : 2);  // q / k / v
    float bv[4];
    for (int j = 0; j < 4; ++j)
        bv[j] = bias[n0 + wn * 64 + j * 16 + l15];
    float scl = (mode == 0) ? CS : 1.0f;

    for (int i = 0; i < 4; ++i) {
        __syncthreads();
        for (int j = 0; j < 4; ++j)
            for (int v = 0; v < 4; ++v)
                Et[(wm * 16 + quad * 4 + v) * 136 + wn * 64 + j * 16 + l15] =
                    __float2bfloat16((acc[i][j][v] + bv[j]) * scl);
        __syncthreads();
        if (mode < 2) {
            int r = tid >> 3, cc = (tid & 7) * 16;
            int m = m0 + i * 16 + (r < 16 ? r : r + 48);
            int b = m >> 11, t = m & 2047;
            int n = (n0 & 1023) + cc;
            int h = n >> 6, d = n & 63;
            bf16* dst = (mode == 0 ? qb : kb) + (((size_t)(b * 16 + h)) * T + t) * 64 + d;
            ushort8 u0 = *(const ushort8*)&Et[r * 136 + cc];
            ushort8 u1 = *(const ushort8*)&Et[r * 136 + cc + 8];
            *(ushort8*)dst = u0;
            *(ushort8*)(dst + 8) = u1;
        } else {
            int run = tid >> 7, d = tid & 127;
            int t0 = m0 + i * 16 + run * 64;
            int b = t0 >> 11, tt = t0 & 2047;
            int n = (n0 & 1023) + d;
            int h = n >> 6, dd = n & 63;
            __align__(16) bf16 tmp[16];
            for (int jj = 0; jj < 16; ++jj)
                tmp[jj] = Et[(run * 16 + jj) * 136 + d];
            bf16* dst = vTb + (((size_t)(b * 16 + h)) * 64 + dd) * T + tt;
            *(ushort8*)dst = *(const ushort8*)tmp;
            *(ushort8*)(dst + 8) = *(const ushort8*)(tmp + 8);
        }
    }
}

// ---------------- Flash attention (causal), S^T formulation, 128q x 64k tiles ----------
// Pipeline: K double-buffered via gld_lds; V reg-staged (T14); Pl stride-64
// rows with 16B-unit XOR swizzle. Softmax finish: raw v_exp_f32 + packed
// v_cvt_pk_bf16_f32.
__global__ __launch_bounds__(256, 4) void flash_attn(const bf16* __restrict__ qb,
                                                     const bf16* __restrict__ kbuf,
                                                     const bf16* __restrict__ vT,
                                                     bf16* __restrict__ ob) {
    constexpr int T = 2048;
    __shared__ __align__(16) bf16 Kl[2][64 * 64];  // [key][d], 8-elem d-blocks XOR-swizzled
    __shared__ __align__(16) bf16 Vl[64 * 64];     // [d][key], 8-elem key-blocks XOR-swizzled
    __shared__ __align__(16) bf16 Pl[128 * 64];    // [wave*2+s -> 16 rows][key], unit-swizzled
    int tid = threadIdx.x;
    int lane = tid & 63, w = tid >> 6;
    int l15 = lane & 15, quad = lane >> 4;

    int g = blockIdx.x;
    int quarter = g >> 8;          // 0..3
    int j = (g >> 6) & 3;          // 0..3
    int bh = g & 63;
    int xq;
    switch (quarter) {             // column sums over quarters = 30 for every j
        case 0:  xq = 15 - j; break;
        case 1:  xq = 8 + j;  break;
        case 2:  xq = 4 + j;  break;
        default: xq = 3 - j;  break;
    }
    int q0 = xq << 7;
    const bf16* qbase = qb   + (size_t)bh * T * 64;
    const bf16* kbase = kbuf + (size_t)bh * T * 64;
    const bf16* vbase = vT   + (size_t)bh * 64 * T;

    int qg[2];
    bf16x8 qa[2][2];
#pragma unroll
    for (int s = 0; s < 2; ++s) {
        qg[s] = q0 + w * 32 + s * 16 + l15;
#pragma unroll
        for (int c = 0; c < 2; ++c)
            qa[s][c] = *(const bf16x8*)(qbase + (size_t)qg[s] * 64 + c * 32 + quad * 8);
    }

    bf16x8 ones;
#pragma unroll
    for (int i = 0; i < 8; ++i) ones[i] = (__bf16)1.0f;

    f32x4 O[2][4] = {};
    f32x4 O1[2] = {};
    int h7 = l15 & 7;

    // staging geometry (per thread, 2 chunks x {K,V}, 16B each)
    int off0 = tid * 8, off1 = (256 + tid) * 8;
    int r0 = off0 >> 6, cb0 = (off0 >> 3) & 7;
    int r1 = off1 >> 6, cb1 = (off1 >> 3) & 7;
    int kc0 = (cb0 ^ (r0 & 7)) << 3, kc1 = (cb1 ^ (r1 & 7)) << 3;

    int prow0 = w * 32 + l15;      // Pl row for s=0 (s=1: +16); (prow & 7) == h7
    int nit = 2 * xq + 2;

    // prologue: V(0) -> regs -> Vl; K(0) -> gld_lds -> Kl[0]
    bf16x8 vr0 = *(const bf16x8*)(vbase + (size_t)r0 * T + kc0);
    bf16x8 vr1 = *(const bf16x8*)(vbase + (size_t)r1 * T + kc1);
    gld_lds16(kbase + (size_t)r0 * 64 + kc0, &Kl[0][off0]);
    gld_lds16(kbase + (size_t)r1 * 64 + kc1, &Kl[0][off1]);
    *(bf16x8*)&Vl[off0] = vr0;
    *(bf16x8*)&Vl[off1] = vr1;

    for (int t = 0; t < nit; ++t) {
        int cur = t & 1;
        // drains vmcnt(0)+lgkmcnt(0): Kl[cur] ready, Vl(t) writes visible,
        // and everyone is done with Kl[cur^1]
        __syncthreads();
        bool pre = (t + 1 < nit);
        if (pre) {  // issue V loads FIRST (older in vmcnt), then K prefetch
            int kb2 = (t + 1) << 6, nxt = cur ^ 1;
            vr0 = *(const bf16x8*)(vbase + (size_t)r0 * T + kb2 + kc0);
            vr1 = *(const bf16x8*)(vbase + (size_t)r1 * T + kb2 + kc1);
            gld_lds16(kbase + (size_t)(kb2 + r0) * 64 + kc0, &Kl[nxt][off0]);
            gld_lds16(kbase + (size_t)(kb2 + r1) * 64 + kc1, &Kl[nxt][off1]);
        }
        int kb = t << 6;
        bool maskt = (t >= nit - 2);

        // QK^T + exp2 + causal mask -> Pl (unit-swizzled stride-64 rows)
#pragma unroll
        for (int jn = 0; jn < 4; ++jn) {
            int row = jn * 16 + l15;  // key row in Kl
            bf16x8 a0 = *(const bf16x8*)&Kl[cur][row * 64 + ((quad ^ h7) << 3)];
            bf16x8 a1 = *(const bf16x8*)&Kl[cur][row * 64 + (((4 + quad) ^ h7) << 3)];
            f32x4 sa[2] = {};
            __builtin_amdgcn_s_setprio(1);
            sa[0] = __builtin_amdgcn_mfma_f32_16x16x32_bf16(a0, qa[0][0], sa[0], 0, 0, 0);
            sa[0] = __builtin_amdgcn_mfma_f32_16x16x32_bf16(a1, qa[0][1], sa[0], 0, 0, 0);
            sa[1] = __builtin_amdgcn_mfma_f32_16x16x32_bf16(a0, qa[1][0], sa[1], 0, 0, 0);
            sa[1] = __builtin_amdgcn_mfma_f32_16x16x32_bf16(a1, qa[1][1], sa[1], 0, 0, 0);
            __builtin_amdgcn_s_setprio(0);
            int ubase = jn * 2 + (quad >> 1);   // 16B unit within Pl row
            int lowo = (quad & 1) << 2;         // 8B half within the unit
#pragma unroll
            for (int s = 0; s < 2; ++s) {
                float p[4];
#pragma unroll
                for (int v = 0; v < 4; ++v) {
                    float e = __builtin_amdgcn_exp2f(sa[s][v]);
                    if (maskt) {
                        int key = kb + jn * 16 + quad * 4 + v;
                        e = (key <= qg[s]) ? e : 0.f;
                    }
                    p[v] = e;
                }
                unsigned lo, hi;
                asm("v_cvt_pk_bf16_f32 %0, %1, %2" : "=v"(lo) : "v"(p[0]), "v"(p[1]));
                asm("v_cvt_pk_bf16_f32 %0, %1, %2" : "=v"(hi) : "v"(p[2]), "v"(p[3]));
                uint2v pv;
                pv[0] = lo;
                pv[1] = hi;
                int prow = prow0 + s * 16;
                *(uint2v*)&Pl[prow * 64 + ((ubase ^ h7) << 3) + lowo] = pv;
            }
        }
        asm volatile("s_waitcnt lgkmcnt(0)" ::: "memory");
        bf16x8 pf[2][2];
#pragma unroll
        for (int s = 0; s < 2; ++s) {
            int prow = prow0 + s * 16;
#pragma unroll
            for (int c = 0; c < 2; ++c)
                pf[s][c] = *(const bf16x8*)&Pl[prow * 64 + (((c * 4 + quad) ^ h7) << 3)];
        }

        // lsum via ones-column MFMA (same lane mapping as O -> no shuffles)
        __builtin_amdgcn_s_setprio(1);
#pragma unroll
        for (int s = 0; s < 2; ++s) {
            O1[s] = __builtin_amdgcn_mfma_f32_16x16x32_bf16(pf[s][0], ones, O1[s], 0, 0, 0);
            O1[s] = __builtin_amdgcn_mfma_f32_16x16x32_bf16(pf[s][1], ones, O1[s], 0, 0, 0);
        }
        __builtin_amdgcn_s_setprio(0);

#pragma unroll
        for (int jd = 0; jd < 4; ++jd) {
            int vrow = jd * 16 + l15;  // d row in Vl
            bf16x8 v0 = *(const bf16x8*)&Vl[vrow * 64 + ((quad ^ h7) << 3)];
            bf16x8 v1 = *(const bf16x8*)&Vl[vrow * 64 + (((4 + quad) ^ h7) << 3)];
            __builtin_amdgcn_s_setprio(1);
            O[0][jd] = __builtin_amdgcn_mfma_f32_16x16x32_bf16(pf[0][0], v0, O[0][jd], 0, 0, 0);
            O[0][jd] = __builtin_amdgcn_mfma_f32_16x16x32_bf16(pf[0][1], v1, O[0][jd], 0, 0, 0);
            O[1][jd] = __builtin_amdgcn_mfma_f32_16x16x32_bf16(pf[1][0], v0, O[1][jd], 0, 0, 0);
            O[1][jd] = __builtin_amdgcn_mfma_f32_16x16x32_bf16(pf[1][1], v1, O[1][jd], 0, 0, 0);
            __builtin_amdgcn_s_setprio(0);
        }

        // all waves finished reading Vl(t) (their PV MFMAs forced lgkmcnt on
        // the last Vl reads before reaching this barrier) -> safe to overwrite
        __builtin_amdgcn_s_barrier();
        if (pre) {  // compiler inserts vmcnt(2) here: V loads done, K in flight
            *(bf16x8*)&Vl[off0] = vr0;
            *(bf16x8*)&Vl[off1] = vr1;
        }
    }

    // O1[s][v] = sum_k P[qrow=quad*4+v][k]  (same lane as O[s][jd][v])
    int b = bh >> 4, h = bh & 15;
#pragma unroll
    for (int s = 0; s < 2; ++s) {
        float linv[4];
#pragma unroll
        for (int v = 0; v < 4; ++v) linv[v] = 1.f / O1[s][v];
#pragma unroll
        for (int jd = 0; jd < 4; ++jd) {
#pragma unroll
            for (int v = 0; v < 4; ++v) {
                int qr = q0 + w * 32 + s * 16 + quad * 4 + v;
                ob[((size_t)(b * T + qr)) * 1024 + h * 64 + jd * 16 + l15] =
                    __float2bfloat16(O[s][jd][v] * linv[v]);
            }
        }
    }
}

// ---------------- GEMM2: out = O @ w_proj + b_proj (fp32 out) ----------------
// Same pipelined K-loop as gemm_qkv.
__global__ __launch_bounds__(256) void gemm_proj(const bf16* __restrict__ A,
                                                 const bf16* __restrict__ Bt,
                                                 const float* __restrict__ bias,
                                                 float* __restrict__ out) {
    constexpr int K = 1024, N = 1024;
    __shared__ __align__(16) bf16 Al[2][128 * 32];
    __shared__ __align__(16) bf16 Bl[2][128 * 32];
    int tid = threadIdx.x;
    int lane = tid & 63, w = tid >> 6;
    int wm = w >> 1, wn = w & 1;
    int l15 = lane & 15, quad = lane >> 4;
    int m0 = blockIdx.x * 128, n0 = blockIdx.y * 128;
    int l3 = l15 & 3;

    int e0 = tid * 8, e1 = (256 + tid) * 8;
    int r0 = e0 >> 5, cs0 = ((((e0 >> 3) & 3) ^ (r0 & 3)) << 3);
    int r1 = e1 >> 5, cs1 = ((((e1 >> 3) & 3) ^ (r1 & 3)) << 3);

    f32x4 acc[4][4] = {};
    gld_lds16(A  + (size_t)(m0 + r0) * K + cs0, &Al[0][e0]);
    gld_lds16(Bt + (size_t)(n0 + r0) * K + cs0, &Bl[0][e0]);
    gld_lds16(A  + (size_t)(m0 + r1) * K + cs1, &Al[0][e1]);
    gld_lds16(Bt + (size_t)(n0 + r1) * K + cs1, &Bl[0][e1]);

    for (int t = 0; t < K / 32; ++t) {
        int cur = t & 1;
        __syncthreads();
        if (t + 1 < K / 32) {
            int k2 = (t + 1) * 32, nxt = cur ^ 1;
            gld_lds16(A  + (size_t)(m0 + r0) * K + k2 + cs0, &Al[nxt][e0]);
            gld_lds16(Bt + (size_t)(n0 + r0) * K + k2 + cs0, &Bl[nxt][e0]);
            gld_lds16(A  + (size_t)(m0 + r1) * K + k2 + cs1, &Al[nxt][e1]);
            gld_lds16(Bt + (size_t)(n0 + r1) * K + k2 + cs1, &Bl[nxt][e1]);
        }
        bf16x8 af[4], bfr[4];
        for (int i = 0; i < 4; ++i)
            af[i] = *(const bf16x8*)&Al[cur][(wm * 64 + i * 16 + l15) * 32 + ((quad ^ l3) << 3)];
        for (int j = 0; j < 4; ++j)
            bfr[j] = *(const bf16x8*)&Bl[cur][(wn * 64 + j * 16 + l15) * 32 + ((quad ^ l3) << 3)];
        for (int i = 0; i < 4; ++i)
            for (int j = 0; j < 4; ++j)
                acc[i][j] = __builtin_amdgcn_mfma_f32_16x16x32_bf16(af[i], bfr[j], acc[i][j], 0, 0, 0);
    }
    for (int i = 0; i < 4; ++i) {
        int mbase = m0 + wm * 64 + i * 16 + quad * 4;
        for (int j = 0; j < 4; ++j) {
            int n = n0 + wn * 64 + j * 16 + l15;
            float bv = bias[n];
            for (int v = 0; v < 4; ++v)
                out[(size_t)(mbase + v) * N + n] = acc[i][j][v] + bv;
        }
    }
}

extern "C" void kernel_launch(void* const* d_in, const int* in_sizes, int n_in,
                              void* d_out, int out_size, void* d_ws, size_t ws_size,
                              hipStream_t stream) {
    (void)in_sizes; (void)n_in; (void)out_size; (void)ws_size;
    const float* x      = (const float*)d_in[0];
    const float* w_qkv  = (const float*)d_in[1];
    const float* b_qkv  = (const float*)d_in[2];
    const float* w_proj = (const float*)d_in[3];
    const float* b_proj = (const float*)d_in[4];
    float* out = (float*)d_out;

    char* ws = (char*)d_ws;
    bf16* xb     = (bf16*)(ws);                 // 16 MB [8192][1024]
    bf16* wqkvT  = (bf16*)(ws + (16u << 20));   //  6 MB [3072][1024]
    bf16* wprojT = (bf16*)(ws + (22u << 20));   //  2 MB [1024][1024]
    bf16* qbuf   = (bf16*)(ws + (24u << 20));   // 16 MB [B,H,T,D] (pre-scaled by CS)
    bf16* kbuf   = (bf16*)(ws + (40u << 20));   // 16 MB [B,H,T,D]
    bf16* vTb    = (bf16*)(ws + (72u << 20));   // 16 MB [B,H,D,T] (written by gemm_qkv)
    bf16* ob     = (bf16*)(ws + (56u << 20));   // 16 MB [8192][1024]

    cast_f32_bf16<<<8192, 256, 0, stream>>>(x, xb, 8192 * 1024 / 4);
    transpose_cast<<<dim3(3072 / 32, 1024 / 32), 256, 0, stream>>>(w_qkv, wqkvT, 1024, 3072);
    transpose_cast<<<dim3(1024 / 32, 1024 / 32), 256, 0, stream>>>(w_proj, wprojT, 1024, 1024);
    gemm_qkv<<<dim3(64, 24), 256, 0, stream>>>(xb, wqkvT, b_qkv, qbuf, kbuf, vTb);
    flash_attn<<<1024, 256, 0, stream>>>(qbuf, kbuf, vTb, ob);
    gemm_proj<<<dim3(64, 8), 256, 0, stream>>>(ob, wprojT, b_proj, out);
}

// Round 6
// 244.891 us; speedup vs baseline: 1.0616x; 1.0616x over previous
//
#include <hip/hip_runtime.h>
#include <hip/hip_bf16.h>
#include <math.h>

using bf16 = __hip_bfloat16;
typedef __bf16 bf16x8 __attribute__((ext_vector_type(8)));
typedef float  f32x4  __attribute__((ext_vector_type(4)));
typedef unsigned short ushort8 __attribute__((ext_vector_type(8)));
typedef unsigned uint2v __attribute__((ext_vector_type(2)));

#define DEV __device__ __forceinline__

DEV void gld_lds16(const void* g, void* l) {
    __builtin_amdgcn_global_load_lds((const __attribute__((address_space(1))) void*)g,
                                     (__attribute__((address_space(3))) void*)l,
                                     16, 0, 0);
}

// ---------------- cast fp32 -> bf16 (flat) ----------------
__global__ __launch_bounds__(256) void cast_f32_bf16(const float* __restrict__ in,
                                                     bf16* __restrict__ out, int n4) {
    int i = blockIdx.x * blockDim.x + threadIdx.x;
    if (i >= n4) return;
    float4 f = ((const float4*)in)[i];
    __align__(8) bf16 o[4] = {__float2bfloat16(f.x), __float2bfloat16(f.y),
                              __float2bfloat16(f.z), __float2bfloat16(f.w)};
    ((uint64_t*)out)[i] = *(const uint64_t*)o;
}

// ---------------- transpose + cast: in fp32 [R][Cn] -> out bf16 [Cn][R] ----------------
__global__ __launch_bounds__(256) void transpose_cast(const float* __restrict__ in,
                                                      bf16* __restrict__ out, int R, int Cn) {
    __shared__ float tile[32][33];
    int bx = blockIdx.x * 32;
    int by = blockIdx.y * 32;
    int tx = threadIdx.x & 31, ty = threadIdx.x >> 5;
    for (int i = ty; i < 32; i += 8)
        tile[i][tx] = in[(size_t)(by + i) * Cn + bx + tx];
    __syncthreads();
    for (int i = ty; i < 32; i += 8)
        out[(size_t)(bx + i) * R + by + tx] = __float2bfloat16(tile[tx][i]);
}

// ---------------- GEMM1: qkv = x @ w_qkv + b -> q (prescaled), k, vT ----------------
// Round-4 two-barrier structure (static single-buffer K-loop: compiler folds
// all staging addresses, VALUBusy 17%) with BK=64: halves the number of
// barrier-drain events (16 vs 32), amortizing the exposed stage latency over
// 2x the compute. 64-col rows (128B stride, bank-neutral) use the flash-
// proven 8-unit XOR swizzle: source unit u^(r&7) pre-swizzled globally (LDS
// dest linear per gld_lds rules), fragments read at (hk*4+quad)^(l15&7);
// double-XOR cancels (fragment row &7 == l15&7), ~2-way conflicts (free).
__global__ __launch_bounds__(256) void gemm_qkv(const bf16* __restrict__ A,
                                                const bf16* __restrict__ Bt,
                                                const float* __restrict__ bias,
                                                bf16* __restrict__ qb,
                                                bf16* __restrict__ kb,
                                                bf16* __restrict__ vTb) {
    constexpr int K = 1024, T = 2048;
    constexpr float CS = 0.18033688f;  // 0.125 * log2(e)
    __shared__ __align__(16) bf16 Al[128 * 64];
    __shared__ __align__(16) bf16 Bl[128 * 64];
    __shared__ __align__(16) bf16 Et[32 * 136];  // epilogue staging, pad->272B rows
    int tid = threadIdx.x;
    int lane = tid & 63, w = tid >> 6;
    int wm = w >> 1, wn = w & 1;
    int l15 = lane & 15, quad = lane >> 4;
    int m0 = blockIdx.x * 128, n0 = blockIdx.y * 128;
    int h7 = l15 & 7;

    f32x4 acc[4][4] = {};
    for (int k0 = 0; k0 < K; k0 += 64) {
        __syncthreads();
        for (int it = 0; it < 4; ++it) {
            int e = (it * 256 + tid) * 8;
            int r = e >> 6, u = (e >> 3) & 7;
            int cs = (u ^ (r & 7)) << 3;  // pre-swizzled source k-unit
            gld_lds16(A  + (size_t)(m0 + r) * K + k0 + cs, &Al[e]);
            gld_lds16(Bt + (size_t)(n0 + r) * K + k0 + cs, &Bl[e]);
        }
        __syncthreads();
        for (int hk = 0; hk < 2; ++hk) {
            bf16x8 af[4], bfr[4];
            for (int i = 0; i < 4; ++i)
                af[i] = *(const bf16x8*)&Al[(wm * 64 + i * 16 + l15) * 64 +
                                            (((hk * 4 + quad) ^ h7) << 3)];
            for (int j = 0; j < 4; ++j)
                bfr[j] = *(const bf16x8*)&Bl[(wn * 64 + j * 16 + l15) * 64 +
                                             (((hk * 4 + quad) ^ h7) << 3)];
            for (int i = 0; i < 4; ++i)
                for (int j = 0; j < 4; ++j)
                    acc[i][j] = __builtin_amdgcn_mfma_f32_16x16x32_bf16(af[i], bfr[j], acc[i][j], 0, 0, 0);
        }
    }

    int mode = (blockIdx.y < 8) ? 0 : (blockIdx.y < 16 ? 1 : 2);  // q / k / v
    float bv[4];
    for (int j = 0; j < 4; ++j)
        bv[j] = bias[n0 + wn * 64 + j * 16 + l15];
    float scl = (mode == 0) ? CS : 1.0f;

    for (int i = 0; i < 4; ++i) {
        __syncthreads();
        for (int j = 0; j < 4; ++j)
            for (int v = 0; v < 4; ++v)
                Et[(wm * 16 + quad * 4 + v) * 136 + wn * 64 + j * 16 + l15] =
                    __float2bfloat16((acc[i][j][v] + bv[j]) * scl);
        __syncthreads();
        if (mode < 2) {
            int r = tid >> 3, cc = (tid & 7) * 16;
            int m = m0 + i * 16 + (r < 16 ? r : r + 48);
            int b = m >> 11, t = m & 2047;
            int n = (n0 & 1023) + cc;
            int h = n >> 6, d = n & 63;
            bf16* dst = (mode == 0 ? qb : kb) + (((size_t)(b * 16 + h)) * T + t) * 64 + d;
            ushort8 u0 = *(const ushort8*)&Et[r * 136 + cc];
            ushort8 u1 = *(const ushort8*)&Et[r * 136 + cc + 8];
            *(ushort8*)dst = u0;
            *(ushort8*)(dst + 8) = u1;
        } else {
            int run = tid >> 7, d = tid & 127;
            int t0 = m0 + i * 16 + run * 64;
            int b = t0 >> 11, tt = t0 & 2047;
            int n = (n0 & 1023) + d;
            int h = n >> 6, dd = n & 63;
            __align__(16) bf16 tmp[16];
            for (int jj = 0; jj < 16; ++jj)
                tmp[jj] = Et[(run * 16 + jj) * 136 + d];
            bf16* dst = vTb + (((size_t)(b * 16 + h)) * 64 + dd) * T + tt;
            *(ushort8*)dst = *(const ushort8*)tmp;
            *(ushort8*)(dst + 8) = *(const ushort8*)(tmp + 8);
        }
    }
}

// ---------------- Flash attention (causal), S^T formulation, 128q x 64k tiles ----------
// Pipeline: K double-buffered via gld_lds; V reg-staged (T14); Pl stride-64
// rows with 16B-unit XOR swizzle. Softmax finish: raw v_exp_f32 + packed
// v_cvt_pk_bf16_f32.
__global__ __launch_bounds__(256, 4) void flash_attn(const bf16* __restrict__ qb,
                                                     const bf16* __restrict__ kbuf,
                                                     const bf16* __restrict__ vT,
                                                     bf16* __restrict__ ob) {
    constexpr int T = 2048;
    __shared__ __align__(16) bf16 Kl[2][64 * 64];  // [key][d], 8-elem d-blocks XOR-swizzled
    __shared__ __align__(16) bf16 Vl[64 * 64];     // [d][key], 8-elem key-blocks XOR-swizzled
    __shared__ __align__(16) bf16 Pl[128 * 64];    // [wave*2+s -> 16 rows][key], unit-swizzled
    int tid = threadIdx.x;
    int lane = tid & 63, w = tid >> 6;
    int l15 = lane & 15, quad = lane >> 4;

    int g = blockIdx.x;
    int quarter = g >> 8;          // 0..3
    int j = (g >> 6) & 3;          // 0..3
    int bh = g & 63;
    int xq;
    switch (quarter) {             // column sums over quarters = 30 for every j
        case 0:  xq = 15 - j; break;
        case 1:  xq = 8 + j;  break;
        case 2:  xq = 4 + j;  break;
        default: xq = 3 - j;  break;
    }
    int q0 = xq << 7;
    const bf16* qbase = qb   + (size_t)bh * T * 64;
    const bf16* kbase = kbuf + (size_t)bh * T * 64;
    const bf16* vbase = vT   + (size_t)bh * 64 * T;

    int qg[2];
    bf16x8 qa[2][2];
#pragma unroll
    for (int s = 0; s < 2; ++s) {
        qg[s] = q0 + w * 32 + s * 16 + l15;
#pragma unroll
        for (int c = 0; c < 2; ++c)
            qa[s][c] = *(const bf16x8*)(qbase + (size_t)qg[s] * 64 + c * 32 + quad * 8);
    }

    bf16x8 ones;
#pragma unroll
    for (int i = 0; i < 8; ++i) ones[i] = (__bf16)1.0f;

    f32x4 O[2][4] = {};
    f32x4 O1[2] = {};
    int h7 = l15 & 7;

    // staging geometry (per thread, 2 chunks x {K,V}, 16B each)
    int off0 = tid * 8, off1 = (256 + tid) * 8;
    int r0 = off0 >> 6, cb0 = (off0 >> 3) & 7;
    int r1 = off1 >> 6, cb1 = (off1 >> 3) & 7;
    int kc0 = (cb0 ^ (r0 & 7)) << 3, kc1 = (cb1 ^ (r1 & 7)) << 3;

    int prow0 = w * 32 + l15;      // Pl row for s=0 (s=1: +16); (prow & 7) == h7
    int nit = 2 * xq + 2;

    // prologue: V(0) -> regs -> Vl; K(0) -> gld_lds -> Kl[0]
    bf16x8 vr0 = *(const bf16x8*)(vbase + (size_t)r0 * T + kc0);
    bf16x8 vr1 = *(const bf16x8*)(vbase + (size_t)r1 * T + kc1);
    gld_lds16(kbase + (size_t)r0 * 64 + kc0, &Kl[0][off0]);
    gld_lds16(kbase + (size_t)r1 * 64 + kc1, &Kl[0][off1]);
    *(bf16x8*)&Vl[off0] = vr0;
    *(bf16x8*)&Vl[off1] = vr1;

    for (int t = 0; t < nit; ++t) {
        int cur = t & 1;
        // drains vmcnt(0)+lgkmcnt(0): Kl[cur] ready, Vl(t) writes visible,
        // and everyone is done with Kl[cur^1]
        __syncthreads();
        bool pre = (t + 1 < nit);
        if (pre) {  // issue V loads FIRST (older in vmcnt), then K prefetch
            int kb2 = (t + 1) << 6, nxt = cur ^ 1;
            vr0 = *(const bf16x8*)(vbase + (size_t)r0 * T + kb2 + kc0);
            vr1 = *(const bf16x8*)(vbase + (size_t)r1 * T + kb2 + kc1);
            gld_lds16(kbase + (size_t)(kb2 + r0) * 64 + kc0, &Kl[nxt][off0]);
            gld_lds16(kbase + (size_t)(kb2 + r1) * 64 + kc1, &Kl[nxt][off1]);
        }
        int kb = t << 6;
        bool maskt = (t >= nit - 2);

        // QK^T + exp2 + causal mask -> Pl (unit-swizzled stride-64 rows)
#pragma unroll
        for (int jn = 0; jn < 4; ++jn) {
            int row = jn * 16 + l15;  // key row in Kl
            bf16x8 a0 = *(const bf16x8*)&Kl[cur][row * 64 + ((quad ^ h7) << 3)];
            bf16x8 a1 = *(const bf16x8*)&Kl[cur][row * 64 + (((4 + quad) ^ h7) << 3)];
            f32x4 sa[2] = {};
            __builtin_amdgcn_s_setprio(1);
            sa[0] = __builtin_amdgcn_mfma_f32_16x16x32_bf16(a0, qa[0][0], sa[0], 0, 0, 0);
            sa[0] = __builtin_amdgcn_mfma_f32_16x16x32_bf16(a1, qa[0][1], sa[0], 0, 0, 0);
            sa[1] = __builtin_amdgcn_mfma_f32_16x16x32_bf16(a0, qa[1][0], sa[1], 0, 0, 0);
            sa[1] = __builtin_amdgcn_mfma_f32_16x16x32_bf16(a1, qa[1][1], sa[1], 0, 0, 0);
            __builtin_amdgcn_s_setprio(0);
            int ubase = jn * 2 + (quad >> 1);   // 16B unit within Pl row
            int lowo = (quad & 1) << 2;         // 8B half within the unit
#pragma unroll
            for (int s = 0; s < 2; ++s) {
                float p[4];
#pragma unroll
                for (int v = 0; v < 4; ++v) {
                    float e = __builtin_amdgcn_exp2f(sa[s][v]);
                    if (maskt) {
                        int key = kb + jn * 16 + quad * 4 + v;
                        e = (key <= qg[s]) ? e : 0.f;
                    }
                    p[v] = e;
                }
                unsigned lo, hi;
                asm("v_cvt_pk_bf16_f32 %0, %1, %2" : "=v"(lo) : "v"(p[0]), "v"(p[1]));
                asm("v_cvt_pk_bf16_f32 %0, %1, %2" : "=v"(hi) : "v"(p[2]), "v"(p[3]));
                uint2v pv;
                pv[0] = lo;
                pv[1] = hi;
                int prow = prow0 + s * 16;
                *(uint2v*)&Pl[prow * 64 + ((ubase ^ h7) << 3) + lowo] = pv;
            }
        }
        asm volatile("s_waitcnt lgkmcnt(0)" ::: "memory");
        bf16x8 pf[2][2];
#pragma unroll
        for (int s = 0; s < 2; ++s) {
            int prow = prow0 + s * 16;
#pragma unroll
            for (int c = 0; c < 2; ++c)
                pf[s][c] = *(const bf16x8*)&Pl[prow * 64 + (((c * 4 + quad) ^ h7) << 3)];
        }

        // lsum via ones-column MFMA (same lane mapping as O -> no shuffles)
        __builtin_amdgcn_s_setprio(1);
#pragma unroll
        for (int s = 0; s < 2; ++s) {
            O1[s] = __builtin_amdgcn_mfma_f32_16x16x32_bf16(pf[s][0], ones, O1[s], 0, 0, 0);
            O1[s] = __builtin_amdgcn_mfma_f32_16x16x32_bf16(pf[s][1], ones, O1[s], 0, 0, 0);
        }
        __builtin_amdgcn_s_setprio(0);

#pragma unroll
        for (int jd = 0; jd < 4; ++jd) {
            int vrow = jd * 16 + l15;  // d row in Vl
            bf16x8 v0 = *(const bf16x8*)&Vl[vrow * 64 + ((quad ^ h7) << 3)];
            bf16x8 v1 = *(const bf16x8*)&Vl[vrow * 64 + (((4 + quad) ^ h7) << 3)];
            __builtin_amdgcn_s_setprio(1);
            O[0][jd] = __builtin_amdgcn_mfma_f32_16x16x32_bf16(pf[0][0], v0, O[0][jd], 0, 0, 0);
            O[0][jd] = __builtin_amdgcn_mfma_f32_16x16x32_bf16(pf[0][1], v1, O[0][jd], 0, 0, 0);
            O[1][jd] = __builtin_amdgcn_mfma_f32_16x16x32_bf16(pf[1][0], v0, O[1][jd], 0, 0, 0);
            O[1][jd] = __builtin_amdgcn_mfma_f32_16x16x32_bf16(pf[1][1], v1, O[1][jd], 0, 0, 0);
            __builtin_amdgcn_s_setprio(0);
        }

        // all waves finished reading Vl(t) (their PV MFMAs forced lgkmcnt on
        // the last Vl reads before reaching this barrier) -> safe to overwrite
        __builtin_amdgcn_s_barrier();
        if (pre) {  // compiler inserts vmcnt(2) here: V loads done, K in flight
            *(bf16x8*)&Vl[off0] = vr0;
            *(bf16x8*)&Vl[off1] = vr1;
        }
    }

    // O1[s][v] = sum_k P[qrow=quad*4+v][k]  (same lane as O[s][jd][v])
    int b = bh >> 4, h = bh & 15;
#pragma unroll
    for (int s = 0; s < 2; ++s) {
        float linv[4];
#pragma unroll
        for (int v = 0; v < 4; ++v) linv[v] = 1.f / O1[s][v];
#pragma unroll
        for (int jd = 0; jd < 4; ++jd) {
#pragma unroll
            for (int v = 0; v < 4; ++v) {
                int qr = q0 + w * 32 + s * 16 + quad * 4 + v;
                ob[((size_t)(b * T + qr)) * 1024 + h * 64 + jd * 16 + l15] =
                    __float2bfloat16(O[s][jd][v] * linv[v]);
            }
        }
    }
}

// ---------------- GEMM2: out = O @ w_proj + b_proj (fp32 out) ----------------
// Same BK=64 two-barrier structure as gemm_qkv.
__global__ __launch_bounds__(256) void gemm_proj(const bf16* __restrict__ A,
                                                 const bf16* __restrict__ Bt,
                                                 const float* __restrict__ bias,
                                                 float* __restrict__ out) {
    constexpr int K = 1024, N = 1024;
    __shared__ __align__(16) bf16 Al[128 * 64];
    __shared__ __align__(16) bf16 Bl[128 * 64];
    int tid = threadIdx.x;
    int lane = tid & 63, w = tid >> 6;
    int wm = w >> 1, wn = w & 1;
    int l15 = lane & 15, quad = lane >> 4;
    int m0 = blockIdx.x * 128, n0 = blockIdx.y * 128;
    int h7 = l15 & 7;

    f32x4 acc[4][4] = {};
    for (int k0 = 0; k0 < K; k0 += 64) {
        __syncthreads();
        for (int it = 0; it < 4; ++it) {
            int e = (it * 256 + tid) * 8;
            int r = e >> 6, u = (e >> 3) & 7;
            int cs = (u ^ (r & 7)) << 3;
            gld_lds16(A  + (size_t)(m0 + r) * K + k0 + cs, &Al[e]);
            gld_lds16(Bt + (size_t)(n0 + r) * K + k0 + cs, &Bl[e]);
        }
        __syncthreads();
        for (int hk = 0; hk < 2; ++hk) {
            bf16x8 af[4], bfr[4];
            for (int i = 0; i < 4; ++i)
                af[i] = *(const bf16x8*)&Al[(wm * 64 + i * 16 + l15) * 64 +
                                            (((hk * 4 + quad) ^ h7) << 3)];
            for (int j = 0; j < 4; ++j)
                bfr[j] = *(const bf16x8*)&Bl[(wn * 64 + j * 16 + l15) * 64 +
                                             (((hk * 4 + quad) ^ h7) << 3)];
            for (int i = 0; i < 4; ++i)
                for (int j = 0; j < 4; ++j)
                    acc[i][j] = __builtin_amdgcn_mfma_f32_16x16x32_bf16(af[i], bfr[j], acc[i][j], 0, 0, 0);
        }
    }
    for (int i = 0; i < 4; ++i) {
        int mbase = m0 + wm * 64 + i * 16 + quad * 4;
        for (int j = 0; j < 4; ++j) {
            int n = n0 + wn * 64 + j * 16 + l15;
            float bv = bias[n];
            for (int v = 0; v < 4; ++v)
                out[(size_t)(mbase + v) * N + n] = acc[i][j][v] + bv;
        }
    }
}

extern "C" void kernel_launch(void* const* d_in, const int* in_sizes, int n_in,
                              void* d_out, int out_size, void* d_ws, size_t ws_size,
                              hipStream_t stream) {
    (void)in_sizes; (void)n_in; (void)out_size; (void)ws_size;
    const float* x      = (const float*)d_in[0];
    const float* w_qkv  = (const float*)d_in[1];
    const float* b_qkv  = (const float*)d_in[2];
    const float* w_proj = (const float*)d_in[3];
    const float* b_proj = (const float*)d_in[4];
    float* out = (float*)d_out;

    char* ws = (char*)d_ws;
    bf16* xb     = (bf16*)(ws);                 // 16 MB [8192][1024]
    bf16* wqkvT  = (bf16*)(ws + (16u << 20));   //  6 MB [3072][1024]
    bf16* wprojT = (bf16*)(ws + (22u << 20));   //  2 MB [1024][1024]
    bf16* qbuf   = (bf16*)(ws + (24u << 20));   // 16 MB [B,H,T,D] (pre-scaled by CS)
    bf16* kbuf   = (bf16*)(ws + (40u << 20));   // 16 MB [B,H,T,D]
    bf16* vTb    = (bf16*)(ws + (72u << 20));   // 16 MB [B,H,D,T] (written by gemm_qkv)
    bf16* ob     = (bf16*)(ws + (56u << 20));   // 16 MB [8192][1024]

    cast_f32_bf16<<<8192, 256, 0, stream>>>(x, xb, 8192 * 1024 / 4);
    transpose_cast<<<dim3(3072 / 32, 1024 / 32), 256, 0, stream>>>(w_qkv, wqkvT, 1024, 3072);
    transpose_cast<<<dim3(1024 / 32, 1024 / 32), 256, 0, stream>>>(w_proj, wprojT, 1024, 1024);
    gemm_qkv<<<dim3(64, 24), 256, 0, stream>>>(xb, wqkvT, b_qkv, qbuf, kbuf, vTb);
    flash_attn<<<1024, 256, 0, stream>>>(qbuf, kbuf, vTb, ob);
    gemm_proj<<<dim3(64, 8), 256, 0, stream>>>(ob, wprojT, b_proj, out);
}

// Round 7
// 241.329 us; speedup vs baseline: 1.0772x; 1.0148x over previous
//
#include <hip/hip_runtime.h>
#include <hip/hip_bf16.h>
#include <math.h>

using bf16 = __hip_bfloat16;
typedef __bf16 bf16x8 __attribute__((ext_vector_type(8)));
typedef float  f32x4  __attribute__((ext_vector_type(4)));
typedef unsigned short ushort8 __attribute__((ext_vector_type(8)));
typedef unsigned uint2v __attribute__((ext_vector_type(2)));

#define DEV __device__ __forceinline__

DEV void gld_lds16(const void* g, void* l) {
    __builtin_amdgcn_global_load_lds((const __attribute__((address_space(1))) void*)g,
                                     (__attribute__((address_space(3))) void*)l,
                                     16, 0, 0);
}

// ---------------- prep: fused cast + both weight transposes (1 launch vs 3) --------
// blocks [0,8192): cast x fp32->bf16 flat
// blocks [8192,11264): transpose_cast w_qkv  (R=1024, Cn=3072, 96x32 tiles)
// blocks [11264,12288): transpose_cast w_proj (R=1024, Cn=1024, 32x32 tiles)
__global__ __launch_bounds__(256) void prep(const float* __restrict__ x,
                                            bf16* __restrict__ xb,
                                            const float* __restrict__ w_qkv,
                                            bf16* __restrict__ wqkvT,
                                            const float* __restrict__ w_proj,
                                            bf16* __restrict__ wprojT) {
    __shared__ float tile[32][33];
    int blk = blockIdx.x;
    int tid = threadIdx.x;
    if (blk < 8192) {
        int i = blk * 256 + tid;
        float4 f = ((const float4*)x)[i];
        __align__(8) bf16 o[4] = {__float2bfloat16(f.x), __float2bfloat16(f.y),
                                  __float2bfloat16(f.z), __float2bfloat16(f.w)};
        ((uint64_t*)xb)[i] = *(const uint64_t*)o;
        return;
    }
    const float* in;
    bf16* out;
    int R, Cn, bx, by;
    if (blk < 11264) {
        int bid = blk - 8192;
        in = w_qkv; out = wqkvT; R = 1024; Cn = 3072;
        bx = (bid % 96) * 32; by = (bid / 96) * 32;
    } else {
        int bid = blk - 11264;
        in = w_proj; out = wprojT; R = 1024; Cn = 1024;
        bx = (bid % 32) * 32; by = (bid / 32) * 32;
    }
    int tx = tid & 31, ty = tid >> 5;
    for (int i = ty; i < 32; i += 8)
        tile[i][tx] = in[(size_t)(by + i) * Cn + bx + tx];
    __syncthreads();
    for (int i = ty; i < 32; i += 8)
        out[(size_t)(bx + i) * R + by + tx] = __float2bfloat16(tile[tx][i]);
}

// ---------------- GEMM1: qkv = x @ w_qkv + b -> q (prescaled), k, vT ----------------
// Round-4 structure: static single-buffer BK=32 K-loop (compiler folds all
// staging addresses: VALUBusy 17%), two barriers per K-step, 25KB LDS ->
// 6 blocks/CU co-residency carries the latency hiding.
__global__ __launch_bounds__(256) void gemm_qkv(const bf16* __restrict__ A,
                                                const bf16* __restrict__ Bt,
                                                const float* __restrict__ bias,
                                                bf16* __restrict__ qb,
                                                bf16* __restrict__ kb,
                                                bf16* __restrict__ vTb) {
    constexpr int K = 1024, T = 2048;
    constexpr float CS = 0.18033688f;  // 0.125 * log2(e)
    __shared__ __align__(16) bf16 Al[128 * 32];
    __shared__ __align__(16) bf16 Bl[128 * 32];
    __shared__ __align__(16) bf16 Et[32 * 136];  // epilogue staging, pad->272B rows
    int tid = threadIdx.x;
    int lane = tid & 63, w = tid >> 6;
    int wm = w >> 1, wn = w & 1;
    int l15 = lane & 15, quad = lane >> 4;
    int m0 = blockIdx.x * 128, n0 = blockIdx.y * 128;
    int l3 = l15 & 3;

    f32x4 acc[4][4] = {};
    for (int k0 = 0; k0 < K; k0 += 32) {
        __syncthreads();
        for (int it = 0; it < 2; ++it) {
            int e = (it * 256 + tid) * 8;
            int r = e >> 5, cu = (e >> 3) & 3;
            int cs = ((cu ^ (r & 3)) << 3);  // pre-swizzled source k-chunk
            gld_lds16(A  + (size_t)(m0 + r) * K + k0 + cs, &Al[e]);
            gld_lds16(Bt + (size_t)(n0 + r) * K + k0 + cs, &Bl[e]);
        }
        __syncthreads();
        bf16x8 af[4], bfr[4];
        for (int i = 0; i < 4; ++i)
            af[i] = *(const bf16x8*)&Al[(wm * 64 + i * 16 + l15) * 32 + ((quad ^ l3) << 3)];
        for (int j = 0; j < 4; ++j)
            bfr[j] = *(const bf16x8*)&Bl[(wn * 64 + j * 16 + l15) * 32 + ((quad ^ l3) << 3)];
        for (int i = 0; i < 4; ++i)
            for (int j = 0; j < 4; ++j)
                acc[i][j] = __builtin_amdgcn_mfma_f32_16x16x32_bf16(af[i], bfr[j], acc[i][j], 0, 0, 0);
    }

    int mode = (blockIdx.y < 8) ? 0 : (blockIdx.y < 16 ? 1 : 2);  // q / k / v
    float bv[4];
    for (int j = 0; j < 4; ++j)
        bv[j] = bias[n0 + wn * 64 + j * 16 + l15];
    float scl = (mode == 0) ? CS : 1.0f;

    for (int i = 0; i < 4; ++i) {
        __syncthreads();
        for (int j = 0; j < 4; ++j)
            for (int v = 0; v < 4; ++v)
                Et[(wm * 16 + quad * 4 + v) * 136 + wn * 64 + j * 16 + l15] =
                    __float2bfloat16((acc[i][j][v] + bv[j]) * scl);
        __syncthreads();
        if (mode < 2) {
            int r = tid >> 3, cc = (tid & 7) * 16;
            int m = m0 + i * 16 + (r < 16 ? r : r + 48);
            int b = m >> 11, t = m & 2047;
            int n = (n0 & 1023) + cc;
            int h = n >> 6, d = n & 63;
            bf16* dst = (mode == 0 ? qb : kb) + (((size_t)(b * 16 + h)) * T + t) * 64 + d;
            ushort8 u0 = *(const ushort8*)&Et[r * 136 + cc];
            ushort8 u1 = *(const ushort8*)&Et[r * 136 + cc + 8];
            *(ushort8*)dst = u0;
            *(ushort8*)(dst + 8) = u1;
        } else {
            int run = tid >> 7, d = tid & 127;
            int t0 = m0 + i * 16 + run * 64;
            int b = t0 >> 11, tt = t0 & 2047;
            int n = (n0 & 1023) + d;
            int h = n >> 6, dd = n & 63;
            __align__(16) bf16 tmp[16];
            for (int jj = 0; jj < 16; ++jj)
                tmp[jj] = Et[(run * 16 + jj) * 136 + d];
            bf16* dst = vTb + (((size_t)(b * 16 + h)) * 64 + dd) * T + tt;
            *(ushort8*)dst = *(const ushort8*)tmp;
            *(ushort8*)(dst + 8) = *(const ushort8*)(tmp + 8);
        }
    }
}

// ---------------- Flash attention (causal), S^T formulation, 128q x 64k tiles ----------
// Pipeline: K double-buffered via gld_lds; V reg-staged (T14); Pl stride-64
// rows with 16B-unit XOR swizzle. Softmax finish: raw v_exp_f32 + packed
// v_cvt_pk_bf16_f32.
__global__ __launch_bounds__(256, 4) void flash_attn(const bf16* __restrict__ qb,
                                                     const bf16* __restrict__ kbuf,
                                                     const bf16* __restrict__ vT,
                                                     bf16* __restrict__ ob) {
    constexpr int T = 2048;
    __shared__ __align__(16) bf16 Kl[2][64 * 64];  // [key][d], 8-elem d-blocks XOR-swizzled
    __shared__ __align__(16) bf16 Vl[64 * 64];     // [d][key], 8-elem key-blocks XOR-swizzled
    __shared__ __align__(16) bf16 Pl[128 * 64];    // [wave*2+s -> 16 rows][key], unit-swizzled
    int tid = threadIdx.x;
    int lane = tid & 63, w = tid >> 6;
    int l15 = lane & 15, quad = lane >> 4;

    int g = blockIdx.x;
    int quarter = g >> 8;          // 0..3
    int j = (g >> 6) & 3;          // 0..3
    int bh = g & 63;
    int xq;
    switch (quarter) {             // column sums over quarters = 30 for every j
        case 0:  xq = 15 - j; break;
        case 1:  xq = 8 + j;  break;
        case 2:  xq = 4 + j;  break;
        default: xq = 3 - j;  break;
    }
    int q0 = xq << 7;
    const bf16* qbase = qb   + (size_t)bh * T * 64;
    const bf16* kbase = kbuf + (size_t)bh * T * 64;
    const bf16* vbase = vT   + (size_t)bh * 64 * T;

    int qg[2];
    bf16x8 qa[2][2];
#pragma unroll
    for (int s = 0; s < 2; ++s) {
        qg[s] = q0 + w * 32 + s * 16 + l15;
#pragma unroll
        for (int c = 0; c < 2; ++c)
            qa[s][c] = *(const bf16x8*)(qbase + (size_t)qg[s] * 64 + c * 32 + quad * 8);
    }

    bf16x8 ones;
#pragma unroll
    for (int i = 0; i < 8; ++i) ones[i] = (__bf16)1.0f;

    f32x4 O[2][4] = {};
    f32x4 O1[2] = {};
    int h7 = l15 & 7;

    // staging geometry (per thread, 2 chunks x {K,V}, 16B each)
    int off0 = tid * 8, off1 = (256 + tid) * 8;
    int r0 = off0 >> 6, cb0 = (off0 >> 3) & 7;
    int r1 = off1 >> 6, cb1 = (off1 >> 3) & 7;
    int kc0 = (cb0 ^ (r0 & 7)) << 3, kc1 = (cb1 ^ (r1 & 7)) << 3;

    int prow0 = w * 32 + l15;      // Pl row for s=0 (s=1: +16); (prow & 7) == h7
    int nit = 2 * xq + 2;

    // prologue: V(0) -> regs -> Vl; K(0) -> gld_lds -> Kl[0]
    bf16x8 vr0 = *(const bf16x8*)(vbase + (size_t)r0 * T + kc0);
    bf16x8 vr1 = *(const bf16x8*)(vbase + (size_t)r1 * T + kc1);
    gld_lds16(kbase + (size_t)r0 * 64 + kc0, &Kl[0][off0]);
    gld_lds16(kbase + (size_t)r1 * 64 + kc1, &Kl[0][off1]);
    *(bf16x8*)&Vl[off0] = vr0;
    *(bf16x8*)&Vl[off1] = vr1;

    for (int t = 0; t < nit; ++t) {
        int cur = t & 1;
        __syncthreads();
        bool pre = (t + 1 < nit);
        if (pre) {  // issue V loads FIRST (older in vmcnt), then K prefetch
            int kb2 = (t + 1) << 6, nxt = cur ^ 1;
            vr0 = *(const bf16x8*)(vbase + (size_t)r0 * T + kb2 + kc0);
            vr1 = *(const bf16x8*)(vbase + (size_t)r1 * T + kb2 + kc1);
            gld_lds16(kbase + (size_t)(kb2 + r0) * 64 + kc0, &Kl[nxt][off0]);
            gld_lds16(kbase + (size_t)(kb2 + r1) * 64 + kc1, &Kl[nxt][off1]);
        }
        int kb = t << 6;
        bool maskt = (t >= nit - 2);

        // QK^T + exp2 + causal mask -> Pl (unit-swizzled stride-64 rows)
#pragma unroll
        for (int jn = 0; jn < 4; ++jn) {
            int row = jn * 16 + l15;  // key row in Kl
            bf16x8 a0 = *(const bf16x8*)&Kl[cur][row * 64 + ((quad ^ h7) << 3)];
            bf16x8 a1 = *(const bf16x8*)&Kl[cur][row * 64 + (((4 + quad) ^ h7) << 3)];
            f32x4 sa[2] = {};
            __builtin_amdgcn_s_setprio(1);
            sa[0] = __builtin_amdgcn_mfma_f32_16x16x32_bf16(a0, qa[0][0], sa[0], 0, 0, 0);
            sa[0] = __builtin_amdgcn_mfma_f32_16x16x32_bf16(a1, qa[0][1], sa[0], 0, 0, 0);
            sa[1] = __builtin_amdgcn_mfma_f32_16x16x32_bf16(a0, qa[1][0], sa[1], 0, 0, 0);
            sa[1] = __builtin_amdgcn_mfma_f32_16x16x32_bf16(a1, qa[1][1], sa[1], 0, 0, 0);
            __builtin_amdgcn_s_setprio(0);
            int ubase = jn * 2 + (quad >> 1);   // 16B unit within Pl row
            int lowo = (quad & 1) << 2;         // 8B half within the unit
#pragma unroll
            for (int s = 0; s < 2; ++s) {
                float p[4];
#pragma unroll
                for (int v = 0; v < 4; ++v) {
                    float e = __builtin_amdgcn_exp2f(sa[s][v]);
                    if (maskt) {
                        int key = kb + jn * 16 + quad * 4 + v;
                        e = (key <= qg[s]) ? e : 0.f;
                    }
                    p[v] = e;
                }
                unsigned lo, hi;
                asm("v_cvt_pk_bf16_f32 %0, %1, %2" : "=v"(lo) : "v"(p[0]), "v"(p[1]));
                asm("v_cvt_pk_bf16_f32 %0, %1, %2" : "=v"(hi) : "v"(p[2]), "v"(p[3]));
                uint2v pv;
                pv[0] = lo;
                pv[1] = hi;
                int prow = prow0 + s * 16;
                *(uint2v*)&Pl[prow * 64 + ((ubase ^ h7) << 3) + lowo] = pv;
            }
        }
        asm volatile("s_waitcnt lgkmcnt(0)" ::: "memory");
        bf16x8 pf[2][2];
#pragma unroll
        for (int s = 0; s < 2; ++s) {
            int prow = prow0 + s * 16;
#pragma unroll
            for (int c = 0; c < 2; ++c)
                pf[s][c] = *(const bf16x8*)&Pl[prow * 64 + (((c * 4 + quad) ^ h7) << 3)];
        }

        // lsum via ones-column MFMA (same lane mapping as O -> no shuffles)
        __builtin_amdgcn_s_setprio(1);
#pragma unroll
        for (int s = 0; s < 2; ++s) {
            O1[s] = __builtin_amdgcn_mfma_f32_16x16x32_bf16(pf[s][0], ones, O1[s], 0, 0, 0);
            O1[s] = __builtin_amdgcn_mfma_f32_16x16x32_bf16(pf[s][1], ones, O1[s], 0, 0, 0);
        }
        __builtin_amdgcn_s_setprio(0);

#pragma unroll
        for (int jd = 0; jd < 4; ++jd) {
            int vrow = jd * 16 + l15;  // d row in Vl
            bf16x8 v0 = *(const bf16x8*)&Vl[vrow * 64 + ((quad ^ h7) << 3)];
            bf16x8 v1 = *(const bf16x8*)&Vl[vrow * 64 + (((4 + quad) ^ h7) << 3)];
            __builtin_amdgcn_s_setprio(1);
            O[0][jd] = __builtin_amdgcn_mfma_f32_16x16x32_bf16(pf[0][0], v0, O[0][jd], 0, 0, 0);
            O[0][jd] = __builtin_amdgcn_mfma_f32_16x16x32_bf16(pf[0][1], v1, O[0][jd], 0, 0, 0);
            O[1][jd] = __builtin_amdgcn_mfma_f32_16x16x32_bf16(pf[1][0], v0, O[1][jd], 0, 0, 0);
            O[1][jd] = __builtin_amdgcn_mfma_f32_16x16x32_bf16(pf[1][1], v1, O[1][jd], 0, 0, 0);
            __builtin_amdgcn_s_setprio(0);
        }

        __builtin_amdgcn_s_barrier();
        if (pre) {
            *(bf16x8*)&Vl[off0] = vr0;
            *(bf16x8*)&Vl[off1] = vr1;
        }
    }

    // O1[s][v] = sum_k P[qrow=quad*4+v][k]  (same lane as O[s][jd][v])
    int b = bh >> 4, h = bh & 15;
#pragma unroll
    for (int s = 0; s < 2; ++s) {
        float linv[4];
#pragma unroll
        for (int v = 0; v < 4; ++v) linv[v] = 1.f / O1[s][v];
#pragma unroll
        for (int jd = 0; jd < 4; ++jd) {
#pragma unroll
            for (int v = 0; v < 4; ++v) {
                int qr = q0 + w * 32 + s * 16 + quad * 4 + v;
                ob[((size_t)(b * T + qr)) * 1024 + h * 64 + jd * 16 + l15] =
                    __float2bfloat16(O[s][jd][v] * linv[v]);
            }
        }
    }
}

// ---------------- GEMM2: out = O @ w_proj + b_proj (fp32 out) ----------------
// Round-4 structure (see gemm_qkv).
__global__ __launch_bounds__(256) void gemm_proj(const bf16* __restrict__ A,
                                                 const bf16* __restrict__ Bt,
                                                 const float* __restrict__ bias,
                                                 float* __restrict__ out) {
    constexpr int K = 1024, N = 1024;
    __shared__ __align__(16) bf16 Al[128 * 32];
    __shared__ __align__(16) bf16 Bl[128 * 32];
    int tid = threadIdx.x;
    int lane = tid & 63, w = tid >> 6;
    int wm = w >> 1, wn = w & 1;
    int l15 = lane & 15, quad = lane >> 4;
    int m0 = blockIdx.x * 128, n0 = blockIdx.y * 128;
    int l3 = l15 & 3;

    f32x4 acc[4][4] = {};
    for (int k0 = 0; k0 < K; k0 += 32) {
        __syncthreads();
        for (int it = 0; it < 2; ++it) {
            int e = (it * 256 + tid) * 8;
            int r = e >> 5, cu = (e >> 3) & 3;
            int cs = ((cu ^ (r & 3)) << 3);
            gld_lds16(A  + (size_t)(m0 + r) * K + k0 + cs, &Al[e]);
            gld_lds16(Bt + (size_t)(n0 + r) * K + k0 + cs, &Bl[e]);
        }
        __syncthreads();
        bf16x8 af[4], bfr[4];
        for (int i = 0; i < 4; ++i)
            af[i] = *(const bf16x8*)&Al[(wm * 64 + i * 16 + l15) * 32 + ((quad ^ l3) << 3)];
        for (int j = 0; j < 4; ++j)
            bfr[j] = *(const bf16x8*)&Bl[(wn * 64 + j * 16 + l15) * 32 + ((quad ^ l3) << 3)];
        for (int i = 0; i < 4; ++i)
            for (int j = 0; j < 4; ++j)
                acc[i][j] = __builtin_amdgcn_mfma_f32_16x16x32_bf16(af[i], bfr[j], acc[i][j], 0, 0, 0);
    }
    for (int i = 0; i < 4; ++i) {
        int mbase = m0 + wm * 64 + i * 16 + quad * 4;
        for (int j = 0; j < 4; ++j) {
            int n = n0 + wn * 64 + j * 16 + l15;
            float bv = bias[n];
            for (int v = 0; v < 4; ++v)
                out[(size_t)(mbase + v) * N + n] = acc[i][j][v] + bv;
        }
    }
}

extern "C" void kernel_launch(void* const* d_in, const int* in_sizes, int n_in,
                              void* d_out, int out_size, void* d_ws, size_t ws_size,
                              hipStream_t stream) {
    (void)in_sizes; (void)n_in; (void)out_size; (void)ws_size;
    const float* x      = (const float*)d_in[0];
    const float* w_qkv  = (const float*)d_in[1];
    const float* b_qkv  = (const float*)d_in[2];
    const float* w_proj = (const float*)d_in[3];
    const float* b_proj = (const float*)d_in[4];
    float* out = (float*)d_out;

    char* ws = (char*)d_ws;
    bf16* xb     = (bf16*)(ws);                 // 16 MB [8192][1024]
    bf16* wqkvT  = (bf16*)(ws + (16u << 20));   //  6 MB [3072][1024]
    bf16* wprojT = (bf16*)(ws + (22u << 20));   //  2 MB [1024][1024]
    bf16* qbuf   = (bf16*)(ws + (24u << 20));   // 16 MB [B,H,T,D] (pre-scaled by CS)
    bf16* kbuf   = (bf16*)(ws + (40u << 20));   // 16 MB [B,H,T,D]
    bf16* vTb    = (bf16*)(ws + (72u << 20));   // 16 MB [B,H,D,T] (written by gemm_qkv)
    bf16* ob     = (bf16*)(ws + (56u << 20));   // 16 MB [8192][1024]

    prep<<<12288, 256, 0, stream>>>(x, xb, w_qkv, wqkvT, w_proj, wprojT);
    gemm_qkv<<<dim3(64, 24), 256, 0, stream>>>(xb, wqkvT, b_qkv, qbuf, kbuf, vTb);
    flash_attn<<<1024, 256, 0, stream>>>(qbuf, kbuf, vTb, ob);
    gemm_proj<<<dim3(64, 8), 256, 0, stream>>>(ob, wprojT, b_proj, out);
}

// Round 8
// 237.241 us; speedup vs baseline: 1.0958x; 1.0172x over previous
//
#include <hip/hip_runtime.h>
#include <hip/hip_bf16.h>
#include <math.h>

using bf16 = __hip_bfloat16;
typedef __bf16 bf16x8 __attribute__((ext_vector_type(8)));
typedef float  f32x4  __attribute__((ext_vector_type(4)));
typedef unsigned short ushort8 __attribute__((ext_vector_type(8)));
typedef unsigned uint4v __attribute__((ext_vector_type(4)));

#define DEV __device__ __forceinline__

DEV void gld_lds16(const void* g, void* l) {
    __builtin_amdgcn_global_load_lds((const __attribute__((address_space(1))) void*)g,
                                     (__attribute__((address_space(3))) void*)l,
                                     16, 0, 0);
}

// ---------------- prep: fused cast + both weight transposes (1 launch vs 3) --------
__global__ __launch_bounds__(256) void prep(const float* __restrict__ x,
                                            bf16* __restrict__ xb,
                                            const float* __restrict__ w_qkv,
                                            bf16* __restrict__ wqkvT,
                                            const float* __restrict__ w_proj,
                                            bf16* __restrict__ wprojT) {
    __shared__ float tile[32][33];
    int blk = blockIdx.x;
    int tid = threadIdx.x;
    if (blk < 8192) {
        int i = blk * 256 + tid;
        float4 f = ((const float4*)x)[i];
        __align__(8) bf16 o[4] = {__float2bfloat16(f.x), __float2bfloat16(f.y),
                                  __float2bfloat16(f.z), __float2bfloat16(f.w)};
        ((uint64_t*)xb)[i] = *(const uint64_t*)o;
        return;
    }
    const float* in;
    bf16* out;
    int R, Cn, bx, by;
    if (blk < 11264) {
        int bid = blk - 8192;
        in = w_qkv; out = wqkvT; R = 1024; Cn = 3072;
        bx = (bid % 96) * 32; by = (bid / 96) * 32;
    } else {
        int bid = blk - 11264;
        in = w_proj; out = wprojT; R = 1024; Cn = 1024;
        bx = (bid % 32) * 32; by = (bid / 32) * 32;
    }
    int tx = tid & 31, ty = tid >> 5;
    for (int i = ty; i < 32; i += 8)
        tile[i][tx] = in[(size_t)(by + i) * Cn + bx + tx];
    __syncthreads();
    for (int i = ty; i < 32; i += 8)
        out[(size_t)(bx + i) * R + by + tx] = __float2bfloat16(tile[tx][i]);
}

// ---------------- GEMM1: qkv = x @ w_qkv + b -> q (prescaled), k, vT ----------------
// Round-4 structure: static single-buffer BK=32 K-loop (compiler folds all
// staging addresses: VALUBusy 17%), two barriers per K-step, 25KB LDS.
__global__ __launch_bounds__(256) void gemm_qkv(const bf16* __restrict__ A,
                                                const bf16* __restrict__ Bt,
                                                const float* __restrict__ bias,
                                                bf16* __restrict__ qb,
                                                bf16* __restrict__ kb,
                                                bf16* __restrict__ vTb) {
    constexpr int K = 1024, T = 2048;
    constexpr float CS = 0.18033688f;  // 0.125 * log2(e)
    __shared__ __align__(16) bf16 Al[128 * 32];
    __shared__ __align__(16) bf16 Bl[128 * 32];
    __shared__ __align__(16) bf16 Et[32 * 136];  // epilogue staging, pad->272B rows
    int tid = threadIdx.x;
    int lane = tid & 63, w = tid >> 6;
    int wm = w >> 1, wn = w & 1;
    int l15 = lane & 15, quad = lane >> 4;
    int m0 = blockIdx.x * 128, n0 = blockIdx.y * 128;
    int l3 = l15 & 3;

    f32x4 acc[4][4] = {};
    for (int k0 = 0; k0 < K; k0 += 32) {
        __syncthreads();
        for (int it = 0; it < 2; ++it) {
            int e = (it * 256 + tid) * 8;
            int r = e >> 5, cu = (e >> 3) & 3;
            int cs = ((cu ^ (r & 3)) << 3);  // pre-swizzled source k-chunk
            gld_lds16(A  + (size_t)(m0 + r) * K + k0 + cs, &Al[e]);
            gld_lds16(Bt + (size_t)(n0 + r) * K + k0 + cs, &Bl[e]);
        }
        __syncthreads();
        bf16x8 af[4], bfr[4];
        for (int i = 0; i < 4; ++i)
            af[i] = *(const bf16x8*)&Al[(wm * 64 + i * 16 + l15) * 32 + ((quad ^ l3) << 3)];
        for (int j = 0; j < 4; ++j)
            bfr[j] = *(const bf16x8*)&Bl[(wn * 64 + j * 16 + l15) * 32 + ((quad ^ l3) << 3)];
        for (int i = 0; i < 4; ++i)
            for (int j = 0; j < 4; ++j)
                acc[i][j] = __builtin_amdgcn_mfma_f32_16x16x32_bf16(af[i], bfr[j], acc[i][j], 0, 0, 0);
    }

    int mode = (blockIdx.y < 8) ? 0 : (blockIdx.y < 16 ? 1 : 2);  // q / k / v
    float bv[4];
    for (int j = 0; j < 4; ++j)
        bv[j] = bias[n0 + wn * 64 + j * 16 + l15];
    float scl = (mode == 0) ? CS : 1.0f;

    for (int i = 0; i < 4; ++i) {
        __syncthreads();
        for (int j = 0; j < 4; ++j)
            for (int v = 0; v < 4; ++v)
                Et[(wm * 16 + quad * 4 + v) * 136 + wn * 64 + j * 16 + l15] =
                    __float2bfloat16((acc[i][j][v] + bv[j]) * scl);
        __syncthreads();
        if (mode < 2) {
            int r = tid >> 3, cc = (tid & 7) * 16;
            int m = m0 + i * 16 + (r < 16 ? r : r + 48);
            int b = m >> 11, t = m & 2047;
            int n = (n0 & 1023) + cc;
            int h = n >> 6, d = n & 63;
            bf16* dst = (mode == 0 ? qb : kb) + (((size_t)(b * 16 + h)) * T + t) * 64 + d;
            ushort8 u0 = *(const ushort8*)&Et[r * 136 + cc];
            ushort8 u1 = *(const ushort8*)&Et[r * 136 + cc + 8];
            *(ushort8*)dst = u0;
            *(ushort8*)(dst + 8) = u1;
        } else {
            int run = tid >> 7, d = tid & 127;
            int t0 = m0 + i * 16 + run * 64;
            int b = t0 >> 11, tt = t0 & 2047;
            int n = (n0 & 1023) + d;
            int h = n >> 6, dd = n & 63;
            __align__(16) bf16 tmp[16];
            for (int jj = 0; jj < 16; ++jj)
                tmp[jj] = Et[(run * 16 + jj) * 136 + d];
            bf16* dst = vTb + (((size_t)(b * 16 + h)) * 64 + dd) * T + tt;
            *(ushort8*)dst = *(const ushort8*)tmp;
            *(ushort8*)(dst + 8) = *(const ushort8*)(tmp + 8);
        }
    }
}

// ---------------- Flash attention (causal), S^T formulation, 128q x 64k tiles ----------
// Pipeline: K double-buffered via gld_lds; V reg-staged (T14). P never touches
// LDS: QK^T output (lane=q@l15, key=jn*16+quad*4+v) is redistributed to the PV
// A-fragment layout (key=c*32+quad*8+j) fully in-register:
//   (X,Y) = (Dq[2c][h], Dq[2c+1][h]);
//   v_permlane32_swap(X,Y)  -> X={X.lo,Y.lo}, Y={X.hi,Y.hi}
//   v_permlane16_swap(X,Y)  -> X=dword h, Y=dword 2+h of pf[c]
// (all 16 (quad,c,d) positions verified against src_quad=2(qt&1)+(d>>1),
//  jn=2c+(qt>>1), h=d&1 — bit-identical to the old Pl write/read pair).
// Removes 8 ds_write + lgkmcnt(0) drain + 8 ds_read_b128 per tile and 16KB LDS.
__global__ __launch_bounds__(256, 4) void flash_attn(const bf16* __restrict__ qb,
                                                     const bf16* __restrict__ kbuf,
                                                     const bf16* __restrict__ vT,
                                                     bf16* __restrict__ ob) {
    constexpr int T = 2048;
    __shared__ __align__(16) bf16 Kl[2][64 * 64];  // [key][d], 8-elem d-blocks XOR-swizzled
    __shared__ __align__(16) bf16 Vl[64 * 64];     // [d][key], 8-elem key-blocks XOR-swizzled
    int tid = threadIdx.x;
    int lane = tid & 63, w = tid >> 6;
    int l15 = lane & 15, quad = lane >> 4;

    int g = blockIdx.x;
    int quarter = g >> 8;          // 0..3
    int j = (g >> 6) & 3;          // 0..3
    int bh = g & 63;
    int xq;
    switch (quarter) {             // column sums over quarters = 30 for every j
        case 0:  xq = 15 - j; break;
        case 1:  xq = 8 + j;  break;
        case 2:  xq = 4 + j;  break;
        default: xq = 3 - j;  break;
    }
    int q0 = xq << 7;
    const bf16* qbase = qb   + (size_t)bh * T * 64;
    const bf16* kbase = kbuf + (size_t)bh * T * 64;
    const bf16* vbase = vT   + (size_t)bh * 64 * T;

    int qg[2];
    bf16x8 qa[2][2];
#pragma unroll
    for (int s = 0; s < 2; ++s) {
        qg[s] = q0 + w * 32 + s * 16 + l15;
#pragma unroll
        for (int c = 0; c < 2; ++c)
            qa[s][c] = *(const bf16x8*)(qbase + (size_t)qg[s] * 64 + c * 32 + quad * 8);
    }

    bf16x8 ones;
#pragma unroll
    for (int i = 0; i < 8; ++i) ones[i] = (__bf16)1.0f;

    f32x4 O[2][4] = {};
    f32x4 O1[2] = {};
    int h7 = l15 & 7;

    // staging geometry (per thread, 2 chunks x {K,V}, 16B each)
    int off0 = tid * 8, off1 = (256 + tid) * 8;
    int r0 = off0 >> 6, cb0 = (off0 >> 3) & 7;
    int r1 = off1 >> 6, cb1 = (off1 >> 3) & 7;
    int kc0 = (cb0 ^ (r0 & 7)) << 3, kc1 = (cb1 ^ (r1 & 7)) << 3;

    int nit = 2 * xq + 2;

    // prologue: V(0) -> regs -> Vl; K(0) -> gld_lds -> Kl[0]
    bf16x8 vr0 = *(const bf16x8*)(vbase + (size_t)r0 * T + kc0);
    bf16x8 vr1 = *(const bf16x8*)(vbase + (size_t)r1 * T + kc1);
    gld_lds16(kbase + (size_t)r0 * 64 + kc0, &Kl[0][off0]);
    gld_lds16(kbase + (size_t)r1 * 64 + kc1, &Kl[0][off1]);
    *(bf16x8*)&Vl[off0] = vr0;
    *(bf16x8*)&Vl[off1] = vr1;

    for (int t = 0; t < nit; ++t) {
        int cur = t & 1;
        __syncthreads();
        bool pre = (t + 1 < nit);
        if (pre) {  // issue V loads FIRST (older in vmcnt), then K prefetch
            int kb2 = (t + 1) << 6, nxt = cur ^ 1;
            vr0 = *(const bf16x8*)(vbase + (size_t)r0 * T + kb2 + kc0);
            vr1 = *(const bf16x8*)(vbase + (size_t)r1 * T + kb2 + kc1);
            gld_lds16(kbase + (size_t)(kb2 + r0) * 64 + kc0, &Kl[nxt][off0]);
            gld_lds16(kbase + (size_t)(kb2 + r1) * 64 + kc1, &Kl[nxt][off1]);
        }
        int kb = t << 6;
        bool maskt = (t >= nit - 2);

        // QK^T + exp2 + causal mask -> packed bf16 pairs in registers
        unsigned Dq[2][4][2];
#pragma unroll
        for (int jn = 0; jn < 4; ++jn) {
            int row = jn * 16 + l15;  // key row in Kl
            bf16x8 a0 = *(const bf16x8*)&Kl[cur][row * 64 + ((quad ^ h7) << 3)];
            bf16x8 a1 = *(const bf16x8*)&Kl[cur][row * 64 + (((4 + quad) ^ h7) << 3)];
            f32x4 sa[2] = {};
            __builtin_amdgcn_s_setprio(1);
            sa[0] = __builtin_amdgcn_mfma_f32_16x16x32_bf16(a0, qa[0][0], sa[0], 0, 0, 0);
            sa[0] = __builtin_amdgcn_mfma_f32_16x16x32_bf16(a1, qa[0][1], sa[0], 0, 0, 0);
            sa[1] = __builtin_amdgcn_mfma_f32_16x16x32_bf16(a0, qa[1][0], sa[1], 0, 0, 0);
            sa[1] = __builtin_amdgcn_mfma_f32_16x16x32_bf16(a1, qa[1][1], sa[1], 0, 0, 0);
            __builtin_amdgcn_s_setprio(0);
#pragma unroll
            for (int s = 0; s < 2; ++s) {
                float p[4];
#pragma unroll
                for (int v = 0; v < 4; ++v) {
                    float e = __builtin_amdgcn_exp2f(sa[s][v]);
                    if (maskt) {
                        int key = kb + jn * 16 + quad * 4 + v;
                        e = (key <= qg[s]) ? e : 0.f;
                    }
                    p[v] = e;
                }
                unsigned lo, hi;
                asm("v_cvt_pk_bf16_f32 %0, %1, %2" : "=v"(lo) : "v"(p[0]), "v"(p[1]));
                asm("v_cvt_pk_bf16_f32 %0, %1, %2" : "=v"(hi) : "v"(p[2]), "v"(p[3]));
                Dq[s][jn][0] = lo;
                Dq[s][jn][1] = hi;
            }
        }

        // In-register redistribution to PV A-fragment layout (see header comment)
        bf16x8 pf[2][2];
#pragma unroll
        for (int s = 0; s < 2; ++s)
#pragma unroll
            for (int c = 0; c < 2; ++c) {
                uint4v wv;
#pragma unroll
                for (int h = 0; h < 2; ++h) {
                    unsigned X = Dq[s][2 * c][h];
                    unsigned Y = Dq[s][2 * c + 1][h];
                    asm("v_permlane32_swap_b32 %0, %1" : "+v"(X), "+v"(Y));
                    asm("v_permlane16_swap_b32 %0, %1" : "+v"(X), "+v"(Y));
                    wv[h]     = X;
                    wv[2 + h] = Y;
                }
                pf[s][c] = __builtin_bit_cast(bf16x8, wv);
            }

        // lsum via ones-column MFMA (same lane mapping as O -> no shuffles)
        __builtin_amdgcn_s_setprio(1);
#pragma unroll
        for (int s = 0; s < 2; ++s) {
            O1[s] = __builtin_amdgcn_mfma_f32_16x16x32_bf16(pf[s][0], ones, O1[s], 0, 0, 0);
            O1[s] = __builtin_amdgcn_mfma_f32_16x16x32_bf16(pf[s][1], ones, O1[s], 0, 0, 0);
        }
        __builtin_amdgcn_s_setprio(0);

#pragma unroll
        for (int jd = 0; jd < 4; ++jd) {
            int vrow = jd * 16 + l15;  // d row in Vl
            bf16x8 v0 = *(const bf16x8*)&Vl[vrow * 64 + ((quad ^ h7) << 3)];
            bf16x8 v1 = *(const bf16x8*)&Vl[vrow * 64 + (((4 + quad) ^ h7) << 3)];
            __builtin_amdgcn_s_setprio(1);
            O[0][jd] = __builtin_amdgcn_mfma_f32_16x16x32_bf16(pf[0][0], v0, O[0][jd], 0, 0, 0);
            O[0][jd] = __builtin_amdgcn_mfma_f32_16x16x32_bf16(pf[0][1], v1, O[0][jd], 0, 0, 0);
            O[1][jd] = __builtin_amdgcn_mfma_f32_16x16x32_bf16(pf[1][0], v0, O[1][jd], 0, 0, 0);
            O[1][jd] = __builtin_amdgcn_mfma_f32_16x16x32_bf16(pf[1][1], v1, O[1][jd], 0, 0, 0);
            __builtin_amdgcn_s_setprio(0);
        }

        // all waves finished reading Vl(t) (their PV MFMAs forced lgkmcnt on
        // the last Vl reads before reaching this barrier) -> safe to overwrite
        __builtin_amdgcn_s_barrier();
        if (pre) {  // compiler inserts vmcnt wait: V loads done, K in flight
            *(bf16x8*)&Vl[off0] = vr0;
            *(bf16x8*)&Vl[off1] = vr1;
        }
    }

    // O1[s][v] = sum_k P[qrow=quad*4+v][k]  (same lane as O[s][jd][v])
    int b = bh >> 4, h = bh & 15;
#pragma unroll
    for (int s = 0; s < 2; ++s) {
        float linv[4];
#pragma unroll
        for (int v = 0; v < 4; ++v) linv[v] = 1.f / O1[s][v];
#pragma unroll
        for (int jd = 0; jd < 4; ++jd) {
#pragma unroll
            for (int v = 0; v < 4; ++v) {
                int qr = q0 + w * 32 + s * 16 + quad * 4 + v;
                ob[((size_t)(b * T + qr)) * 1024 + h * 64 + jd * 16 + l15] =
                    __float2bfloat16(O[s][jd][v] * linv[v]);
            }
        }
    }
}

// ---------------- GEMM2: out = O @ w_proj + b_proj (fp32 out) ----------------
// Round-4 structure (see gemm_qkv).
__global__ __launch_bounds__(256) void gemm_proj(const bf16* __restrict__ A,
                                                 const bf16* __restrict__ Bt,
                                                 const float* __restrict__ bias,
                                                 float* __restrict__ out) {
    constexpr int K = 1024, N = 1024;
    __shared__ __align__(16) bf16 Al[128 * 32];
    __shared__ __align__(16) bf16 Bl[128 * 32];
    int tid = threadIdx.x;
    int lane = tid & 63, w = tid >> 6;
    int wm = w >> 1, wn = w & 1;
    int l15 = lane & 15, quad = lane >> 4;
    int m0 = blockIdx.x * 128, n0 = blockIdx.y * 128;
    int l3 = l15 & 3;

    f32x4 acc[4][4] = {};
    for (int k0 = 0; k0 < K; k0 += 32) {
        __syncthreads();
        for (int it = 0; it < 2; ++it) {
            int e = (it * 256 + tid) * 8;
            int r = e >> 5, cu = (e >> 3) & 3;
            int cs = ((cu ^ (r & 3)) << 3);
            gld_lds16(A  + (size_t)(m0 + r) * K + k0 + cs, &Al[e]);
            gld_lds16(Bt + (size_t)(n0 + r) * K + k0 + cs, &Bl[e]);
        }
        __syncthreads();
        bf16x8 af[4], bfr[4];
        for (int i = 0; i < 4; ++i)
            af[i] = *(const bf16x8*)&Al[(wm * 64 + i * 16 + l15) * 32 + ((quad ^ l3) << 3)];
        for (int j = 0; j < 4; ++j)
            bfr[j] = *(const bf16x8*)&Bl[(wn * 64 + j * 16 + l15) * 32 + ((quad ^ l3) << 3)];
        for (int i = 0; i < 4; ++i)
            for (int j = 0; j < 4; ++j)
                acc[i][j] = __builtin_amdgcn_mfma_f32_16x16x32_bf16(af[i], bfr[j], acc[i][j], 0, 0, 0);
    }
    for (int i = 0; i < 4; ++i) {
        int mbase = m0 + wm * 64 + i * 16 + quad * 4;
        for (int j = 0; j < 4; ++j) {
            int n = n0 + wn * 64 + j * 16 + l15;
            float bv = bias[n];
            for (int v = 0; v < 4; ++v)
                out[(size_t)(mbase + v) * N + n] = acc[i][j][v] + bv;
        }
    }
}

extern "C" void kernel_launch(void* const* d_in, const int* in_sizes, int n_in,
                              void* d_out, int out_size, void* d_ws, size_t ws_size,
                              hipStream_t stream) {
    (void)in_sizes; (void)n_in; (void)out_size; (void)ws_size;
    const float* x      = (const float*)d_in[0];
    const float* w_qkv  = (const float*)d_in[1];
    const float* b_qkv  = (const float*)d_in[2];
    const float* w_proj = (const float*)d_in[3];
    const float* b_proj = (const float*)d_in[4];
    float* out = (float*)d_out;

    char* ws = (char*)d_ws;
    bf16* xb     = (bf16*)(ws);                 // 16 MB [8192][1024]
    bf16* wqkvT  = (bf16*)(ws + (16u << 20));   //  6 MB [3072][1024]
    bf16* wprojT = (bf16*)(ws + (22u << 20));   //  2 MB [1024][1024]
    bf16* qbuf   = (bf16*)(ws + (24u << 20));   // 16 MB [B,H,T,D] (pre-scaled by CS)
    bf16* kbuf   = (bf16*)(ws + (40u << 20));   // 16 MB [B,H,T,D]
    bf16* vTb    = (bf16*)(ws + (72u << 20));   // 16 MB [B,H,D,T] (written by gemm_qkv)
    bf16* ob     = (bf16*)(ws + (56u << 20));   // 16 MB [8192][1024]

    prep<<<12288, 256, 0, stream>>>(x, xb, w_qkv, wqkvT, w_proj, wprojT);
    gemm_qkv<<<dim3(64, 24), 256, 0, stream>>>(xb, wqkvT, b_qkv, qbuf, kbuf, vTb);
    flash_attn<<<1024, 256, 0, stream>>>(qbuf, kbuf, vTb, ob);
    gemm_proj<<<dim3(64, 8), 256, 0, stream>>>(ob, wprojT, b_proj, out);
}